// Round 12
// baseline (539.533 us; speedup 1.0000x reference)
//
#include <hip/hip_runtime.h>

#define BB 8
#define TT 4096
#define DD 768
#define MM (BB*TT)   // 32768

typedef _Float16 f16;
typedef _Float16 f16x8 __attribute__((ext_vector_type(8)));
typedef float f32x4 __attribute__((ext_vector_type(4)));

typedef __attribute__((address_space(1))) void void_g;
typedef __attribute__((address_space(3))) void void_l;

// async global->LDS, 16B per lane. LDS dest = wave-uniform base + lane*16 (linear).
__device__ __forceinline__ void gload16(const void* g, void* l) {
  __builtin_amdgcn_global_load_lds((void_g*)g, (void_l*)l, 16, 0, 0);
}

// ---------------- f32 -> f16 convert (for weight matrices) ----------------
__global__ void cvt_f32_f16(const float* __restrict__ in, f16* __restrict__ out, int n) {
  int i0 = (blockIdx.x * blockDim.x + threadIdx.x) * 8;
  int stride = gridDim.x * blockDim.x * 8;
  for (int i = i0; i < n; i += stride) {
    float4 a = *(const float4*)(in + i);
    float4 b = *(const float4*)(in + i + 4);
    f16x8 o;
    o[0] = (f16)a.x; o[1] = (f16)a.y; o[2] = (f16)a.z; o[3] = (f16)a.w;
    o[4] = (f16)b.x; o[5] = (f16)b.y; o[6] = (f16)b.z; o[7] = (f16)b.w;
    *(f16x8*)(out + i) = o;
  }
}

// ---------------- projection GEMM: C = A*W^T + bias -----------------------
// A: MMxDD f32 (reg-cvt staged); W: DDxDD f16 (gload16 staged, pre-swizzled
// source). frag==0: C row-major (K). frag==1: C in dc-major fragment layout:
// idx = (((row>>6)*24 + (col>>5))*4 + ((row>>4)&3))*512
//       + ((row&15) + ((col>>3)&3)*16)*8 + (col&7)
// so a wave's 8 per-phase A-fragments are two contiguous 4KB runs.
__global__ __launch_bounds__(256)
void proj_gemm(const float* __restrict__ Af, const f16* __restrict__ Wh,
               const float* __restrict__ bias, f16* __restrict__ C, int frag) {
  __shared__ f16 As[128 * 32];
  __shared__ f16 Ws[128 * 32];
  const int m0 = blockIdx.x * 128;
  const int n0 = blockIdx.y * 128;
  const int t = threadIdx.x;
  const int lane = t & 63;
  const int w = t >> 6;
  const int wm = (w >> 1) * 64;
  const int wn = (w & 1) * 64;
  const int fr = lane & 15, fq = lane >> 4;
  const int xst = ((t >> 3) & 3) << 3;   // A store-side swizzle (row = t>>2)
  const int xrd = ((fr >> 1) & 3) << 3;  // read-side swizzle (row = ..+fr)

  f32x4 acc[4][4] = {};

  const int e0 = t * 8;
  const int r0 = t >> 2, cA = (t & 3) * 8;
  const int e1 = 2048 + t * 8;

  // W gload16 source: linear LDS dest slot t / t+256, source col pre-swizzled
  const int c8 = ((t & 3) ^ ((t >> 3) & 3)) * 8;
  const f16* wlo = Wh + (size_t)(n0 + r0) * DD + c8;
  const f16* whi = wlo + (size_t)64 * DD;

  for (int ks = 0; ks < 24; ++ks) {
    const int k0 = ks * 32;
    // stage W (f16, async direct to LDS)
    gload16(wlo + k0, &Ws[w * 512]);
    gload16(whi + k0, &Ws[2048 + w * 512]);
    // reg-stage A with f32->f16 conversion (swizzled store)
    {
      const float* g0 = Af + (size_t)(m0 + r0) * DD + k0 + cA;
      const float* g1 = Af + (size_t)(m0 + 64 + r0) * DD + k0 + cA;
      float4 x0 = *(const float4*)g0, x1 = *(const float4*)(g0 + 4);
      float4 y0 = *(const float4*)g1, y1 = *(const float4*)(g1 + 4);
      f16x8 va, vb;
      va[0] = (f16)x0.x; va[1] = (f16)x0.y; va[2] = (f16)x0.z; va[3] = (f16)x0.w;
      va[4] = (f16)x1.x; va[5] = (f16)x1.y; va[6] = (f16)x1.z; va[7] = (f16)x1.w;
      vb[0] = (f16)y0.x; vb[1] = (f16)y0.y; vb[2] = (f16)y0.z; vb[3] = (f16)y0.w;
      vb[4] = (f16)y1.x; vb[5] = (f16)y1.y; vb[6] = (f16)y1.z; vb[7] = (f16)y1.w;
      *(f16x8*)&As[e0 ^ xst] = va;
      *(f16x8*)&As[e1 ^ xst] = vb;
    }
    __syncthreads();

    f16x8 a[4], b[4];
#pragma unroll
    for (int i = 0; i < 4; ++i)
      a[i] = *(const f16x8*)&As[(((wm + i * 16 + fr) * 32) + fq * 8) ^ xrd];
#pragma unroll
    for (int j = 0; j < 4; ++j)
      b[j] = *(const f16x8*)&Ws[(((wn + j * 16 + fr) * 32) + fq * 8) ^ xrd];
#pragma unroll
    for (int i = 0; i < 4; ++i)
#pragma unroll
      for (int j = 0; j < 4; ++j)
        acc[i][j] = __builtin_amdgcn_mfma_f32_16x16x32_f16(a[i], b[j], acc[i][j], 0, 0, 0);
    __syncthreads();
  }

#pragma unroll
  for (int j = 0; j < 4; ++j) {
    const int col = n0 + wn + j * 16 + fr;
    const float bv = bias[col];
#pragma unroll
    for (int i = 0; i < 4; ++i) {
#pragma unroll
      for (int r = 0; r < 4; ++r) {
        const int row = m0 + wm + i * 16 + fq * 4 + r;
        const f16 v = (f16)(acc[i][j][r] + bv);
        if (frag) {
          const size_t idx = (((size_t)(row >> 6) * 24 + (col >> 5)) * 4 +
                              ((row >> 4) & 3)) * 512 +
                             ((row & 15) + (((col >> 3) & 3) << 4)) * 8 + (col & 7);
          C[idx] = v;
        } else {
          C[(size_t)row * DD + col] = v;
        }
      }
    }
  }
}

// ---------------- attn10: K-step-64 phases, contiguous Qf, no copies ------
// Grid 768: bid = qs*24 + kh*8 + bb (batch -> XCD); kh thirds kt {11,11,10}.
// Block 256 thr = 4 waves (2q x 2k), tile 128q x 128k. Per phase (64 k-cols):
// stage next 16KB K tile (4 gload16), load 8 Q-fragments from 2 contiguous
// 4KB runs (imm offsets), 32 MFMA, ONE barrier. Phases = cnt*12 (was cnt*24).
// (256,3): ~102 arch VGPR + 64 AGPR <= 170 cap -- no spills (tripwire: WRITE).
__global__ __launch_bounds__(256, 3)
void attn10(const f16* __restrict__ Qf, const f16* __restrict__ K,
            const int* __restrict__ mask, float* __restrict__ pzv,
            float* __restrict__ sdg) {
  __shared__ f16 Ks[2][128 * 64];

  const int bid = blockIdx.x;
  const int qs = bid / 24;
  const int kh = (bid % 24) >> 3;
  const int bb = bid & 7;
  const int t = threadIdx.x, l = t & 63, w = t >> 6;
  const int wq = w >> 1, wk = w & 1;
  const int fr = l & 15, fq = l >> 4;
  const int q0 = qs * 128;
  const float scale = 0.036084391824351613f;  // 1/sqrt(768)
  const int lo = kh * 11;
  const int cnt = (kh < 2) ? 11 : 10;
  const int P = cnt * 12;

  const f16* Kg = K + (size_t)bb * TT * DD;

  // Qf base: 64-row group grp = bb*64 + qs*2 + wq; lane offset l*8.
  const int grp = bb * 64 + qs * 2 + wq;
  const f16* qf = Qf + (size_t)grp * 24 * 4 * 512 + (size_t)l * 8;

  // K staging: linear 16B slots; source col-slot pre-swizzled: ^((row>>1)&3).
  const int c8 = ((t & 3) ^ ((t >> 3) & 3)) * 8;
  const f16* klo = Kg + (size_t)(t >> 2) * DD + c8;
  const f16* khi = klo + (size_t)64 * DD;

  // K fragment read: row*32 + (fq ^ ((fr>>1)&3))*8  (conflict-free, measured)
  const int sx = (fq ^ ((fr >> 1) & 3)) * 8;
  const int bbase = (wk * 64 + fr) * 32 + sx;

  f32x4 acc[4][4] = {};
  f32x4 zacc[4] = {};
  int im0 = 1, im1 = 1, im2 = 1, im3 = 1;

  // per phase p: kt = lo + p/12, k-cols [ (p%12)*64, +64 ) of kt's 128-row tile
#define STAGE(bf, p_) do { \
    const size_t o0 = (size_t)(lo + (p_) / 12) * 128 * DD + (size_t)(((p_) % 12) * 64); \
    gload16(klo + o0,      &Ks[bf][w * 512]); \
    gload16(khi + o0,      &Ks[bf][2048 + w * 512]); \
    gload16(klo + o0 + 32, &Ks[bf][4096 + w * 512]); \
    gload16(khi + o0 + 32, &Ks[bf][6144 + w * 512]); \
  } while (0)

  STAGE(0, 0);
  __syncthreads();

  for (int p = 0; p < P; ++p) {
    const int buf = p & 1;
    const int kt = lo + p / 12, pj = p % 12;
    if (p + 1 < P) STAGE(buf ^ 1, p + 1);
    if (pj == 0) {  // preload mask for this kt (consumed at pj==11)
      const int kb = bb * TT + kt * 128 + wk * 64 + fr;
      im0 = mask[kb]; im1 = mask[kb + 16]; im2 = mask[kb + 32]; im3 = mask[kb + 48];
    }

    // 8 Q fragments: two contiguous 4KB runs (imm offsets 0/1024/2048/3072 B)
    const f16* qpA = qf + (size_t)pj * 4096;
    const f16* qpB = qpA + 2048;
    f16x8 avA[4], avB[4];
#pragma unroll
    for (int i = 0; i < 4; ++i) {
      avA[i] = *(const f16x8*)(qpA + i * 512);
      avB[i] = *(const f16x8*)(qpB + i * 512);
    }

    f16x8 bvA[4], bvB[4];
#pragma unroll
    for (int j = 0; j < 4; ++j) bvA[j] = *(const f16x8*)&Ks[buf][bbase + j * 512];
#pragma unroll
    for (int j = 0; j < 4; ++j) bvB[j] = *(const f16x8*)&Ks[buf][4096 + bbase + j * 512];
#pragma unroll
    for (int i = 0; i < 4; ++i)
#pragma unroll
      for (int j = 0; j < 4; ++j)
        acc[i][j] = __builtin_amdgcn_mfma_f32_16x16x32_f16(avA[i], bvA[j], acc[i][j], 0, 0, 0);
#pragma unroll
    for (int i = 0; i < 4; ++i)
#pragma unroll
      for (int j = 0; j < 4; ++j)
        acc[i][j] = __builtin_amdgcn_mfma_f32_16x16x32_f16(avB[i], bvB[j], acc[i][j], 0, 0, 0);

    if (pj == 11) {
      // ---- per-kt epilogue: per-lane exp-sum (no max), diag capture ----
      const float mb0 = im0 ? 0.f : -1e30f;
      const float mb1 = im1 ? 0.f : -1e30f;
      const float mb2 = im2 ? 0.f : -1e30f;
      const float mb3 = im3 ? 0.f : -1e30f;
      const bool isdiag = (kt == qs);
#pragma unroll
      for (int i = 0; i < 4; ++i) {
#pragma unroll
        for (int rg = 0; rg < 4; ++rg) {
          float v0 = fmaf(acc[i][0][rg], scale, mb0);
          float v1 = fmaf(acc[i][1][rg], scale, mb1);
          float v2 = fmaf(acc[i][2][rg], scale, mb2);
          float v3 = fmaf(acc[i][3][rg], scale, mb3);
          if (isdiag) {
            const int rl = wq * 64 + i * 16 + fq * 4 + rg;
            const int cl = wk * 64 + fr;
            if (cl      == rl) sdg[(size_t)bb * TT + q0 + rl] = v0;
            if (cl + 16 == rl) sdg[(size_t)bb * TT + q0 + rl] = v1;
            if (cl + 32 == rl) sdg[(size_t)bb * TT + q0 + rl] = v2;
            if (cl + 48 == rl) sdg[(size_t)bb * TT + q0 + rl] = v3;
          }
          zacc[i][rg] += __expf(v0) + __expf(v1) + __expf(v2) + __expf(v3);
        }
      }
#pragma unroll
      for (int i = 0; i < 4; ++i)
#pragma unroll
        for (int j = 0; j < 4; ++j)
          acc[i][j] = (f32x4)(0.f);
    }

    __syncthreads();
  }
#undef STAGE

  // reduce zacc across the 16 fr-lanes; write per-(kh,wk) partial Z (6 slots)
  const int slot = kh * 2 + wk;
#pragma unroll
  for (int i = 0; i < 4; ++i) {
#pragma unroll
    for (int rg = 0; rg < 4; ++rg) {
      float z = zacc[i][rg];
#pragma unroll
      for (int off = 1; off < 16; off <<= 1) z += __shfl_xor(z, off);
      if (fr == 0) {
        const int row = wq * 64 + i * 16 + fq * 4 + rg;
        pzv[(size_t)slot * MM + bb * TT + q0 + row] = z;
      }
    }
  }
}

// ---------------- merge 6 partials -> wdiag ----------------
__global__ void merge6(const float* __restrict__ pz, const float* __restrict__ sdg,
                       float* __restrict__ wdiag) {
  int i = blockIdx.x * 256 + threadIdx.x;
  if (i >= MM) return;
  float Z = 0.f;
#pragma unroll
  for (int s = 0; s < 6; ++s) Z += pz[(size_t)s * MM + i];
  wdiag[i] = __expf(sdg[i]) / Z;
}

// ---------------- output ----------------
__global__ void zero_out(float* out, int n) {
  int i = blockIdx.x * 256 + threadIdx.x;
  if (i < n) out[i] = 0.f;
}

// out[b,d] = sum_t X[b,t,d] * wdiag[b,t]
__global__ __launch_bounds__(256)
void out_gemv(const float* __restrict__ X, const float* __restrict__ wdiag,
              float* __restrict__ out) {
  __shared__ float wsm[256];
  const int b = blockIdx.z;
  const int d = blockIdx.y * 256 + threadIdx.x;
  const int tbase = blockIdx.x * 256;
  wsm[threadIdx.x] = wdiag[b * TT + tbase + threadIdx.x];
  __syncthreads();
  float acc = 0.f;
  const float* xp = X + (size_t)(b * TT + tbase) * DD + d;
#pragma unroll 4
  for (int i = 0; i < 256; ++i) acc += xp[(size_t)i * DD] * wsm[i];
  atomicAdd(&out[b * DD + d], acc);
}

extern "C" void kernel_launch(void* const* d_in, const int* in_sizes, int n_in,
                              void* d_out, int out_size, void* d_ws, size_t ws_size,
                              hipStream_t stream) {
  const float* X    = (const float*)d_in[0];
  const int*   mask = (const int*)d_in[1];
  const float* Wq_w = (const float*)d_in[2];
  const float* Wq_b = (const float*)d_in[3];
  const float* Wk_w = (const float*)d_in[4];
  const float* Wk_b = (const float*)d_in[5];
  float* out = (float*)d_out;

  // workspace layout (~103 MB):
  // [Qf 50.3MB][Kh 50.3MB][Wqh|Wkh 2.36MB -- aliased after proj by pz|sdg|wdiag]
  f16* Qf  = (f16*)d_ws;                      // fragment-major Q
  f16* Kh  = Qf + (size_t)MM * DD;            // row-major K
  f16* Wqh = Kh + (size_t)MM * DD;            // f16 weights (dead after proj)
  f16* Wkh = Wqh + (size_t)DD * DD;
  float* pz    = (float*)Wqh;                 // alias: written by attn10 after proj reads
  float* sdg   = pz + 6 * (size_t)MM;
  float* wdiag = sdg + MM;

  cvt_f32_f16<<<288, 256, 0, stream>>>(Wq_w, Wqh, DD * DD);
  cvt_f32_f16<<<288, 256, 0, stream>>>(Wk_w, Wkh, DD * DD);

  proj_gemm<<<dim3(256, 6), 256, 0, stream>>>(X, Wqh, Wq_b, Qf, 1);
  proj_gemm<<<dim3(256, 6), 256, 0, stream>>>(X, Wkh, Wk_b, Kh, 0);

  attn10<<<768, 256, 0, stream>>>(Qf, Kh, mask, pz, sdg);

  merge6<<<128, 256, 0, stream>>>(pz, sdg, wdiag);

  zero_out<<<24, 256, 0, stream>>>(out, BB * DD);
  out_gemv<<<dim3(16, 3, 8), 256, 0, stream>>>(X, wdiag, out);
}

// Round 13
// 409.674 us; speedup vs baseline: 1.3170x; 1.3170x over previous
//
#include <hip/hip_runtime.h>

#define BB 8
#define TT 4096
#define DD 768
#define MM (BB*TT)   // 32768

typedef _Float16 f16;
typedef _Float16 f16x8 __attribute__((ext_vector_type(8)));
typedef float f32x4 __attribute__((ext_vector_type(4)));

typedef __attribute__((address_space(1))) void void_g;
typedef __attribute__((address_space(3))) void void_l;

// async global->LDS, 16B per lane. LDS dest = wave-uniform base + lane*16 (linear).
__device__ __forceinline__ void gload16(const void* g, void* l) {
  __builtin_amdgcn_global_load_lds((void_g*)g, (void_l*)l, 16, 0, 0);
}

// ---------------- f32 -> f16 convert (for weight matrices) ----------------
__global__ void cvt_f32_f16(const float* __restrict__ in, f16* __restrict__ out, int n) {
  int i0 = (blockIdx.x * blockDim.x + threadIdx.x) * 8;
  int stride = gridDim.x * blockDim.x * 8;
  for (int i = i0; i < n; i += stride) {
    float4 a = *(const float4*)(in + i);
    float4 b = *(const float4*)(in + i + 4);
    f16x8 o;
    o[0] = (f16)a.x; o[1] = (f16)a.y; o[2] = (f16)a.z; o[3] = (f16)a.w;
    o[4] = (f16)b.x; o[5] = (f16)b.y; o[6] = (f16)b.z; o[7] = (f16)b.w;
    *(f16x8*)(out + i) = o;
  }
}

// ---------------- projection GEMM: C = A*W^T + bias -----------------------
// A: MMxDD f32 (reg-cvt staged); W: DDxDD f16 (gload16 staged, pre-swizzled
// source). frag==0: C row-major (K). frag==1: C in dc-major fragment layout:
// idx = (((row>>6)*24 + (col>>5))*4 + ((row>>4)&3))*512
//       + ((row&15) + ((col>>3)&3)*16)*8 + (col&7)
// -> wave's 4 A-fragments per dc are one contiguous 2KB run.
__global__ __launch_bounds__(256)
void proj_gemm(const float* __restrict__ Af, const f16* __restrict__ Wh,
               const float* __restrict__ bias, f16* __restrict__ C, int frag) {
  __shared__ f16 As[128 * 32];
  __shared__ f16 Ws[128 * 32];
  const int m0 = blockIdx.x * 128;
  const int n0 = blockIdx.y * 128;
  const int t = threadIdx.x;
  const int lane = t & 63;
  const int w = t >> 6;
  const int wm = (w >> 1) * 64;
  const int wn = (w & 1) * 64;
  const int fr = lane & 15, fq = lane >> 4;
  const int xst = ((t >> 3) & 3) << 3;   // A store-side swizzle (row = t>>2)
  const int xrd = ((fr >> 1) & 3) << 3;  // read-side swizzle (row = ..+fr)

  f32x4 acc[4][4] = {};

  const int e0 = t * 8;
  const int r0 = t >> 2, cA = (t & 3) * 8;
  const int e1 = 2048 + t * 8;

  // W gload16 source: linear LDS dest slot t / t+256, source col pre-swizzled
  const int c8 = ((t & 3) ^ ((t >> 3) & 3)) * 8;
  const f16* wlo = Wh + (size_t)(n0 + r0) * DD + c8;
  const f16* whi = wlo + (size_t)64 * DD;

  for (int ks = 0; ks < 24; ++ks) {
    const int k0 = ks * 32;
    // stage W (f16, async direct to LDS)
    gload16(wlo + k0, &Ws[w * 512]);
    gload16(whi + k0, &Ws[2048 + w * 512]);
    // reg-stage A with f32->f16 conversion (swizzled store)
    {
      const float* g0 = Af + (size_t)(m0 + r0) * DD + k0 + cA;
      const float* g1 = Af + (size_t)(m0 + 64 + r0) * DD + k0 + cA;
      float4 x0 = *(const float4*)g0, x1 = *(const float4*)(g0 + 4);
      float4 y0 = *(const float4*)g1, y1 = *(const float4*)(g1 + 4);
      f16x8 va, vb;
      va[0] = (f16)x0.x; va[1] = (f16)x0.y; va[2] = (f16)x0.z; va[3] = (f16)x0.w;
      va[4] = (f16)x1.x; va[5] = (f16)x1.y; va[6] = (f16)x1.z; va[7] = (f16)x1.w;
      vb[0] = (f16)y0.x; vb[1] = (f16)y0.y; vb[2] = (f16)y0.z; vb[3] = (f16)y0.w;
      vb[4] = (f16)y1.x; vb[5] = (f16)y1.y; vb[6] = (f16)y1.z; vb[7] = (f16)y1.w;
      *(f16x8*)&As[e0 ^ xst] = va;
      *(f16x8*)&As[e1 ^ xst] = vb;
    }
    __syncthreads();

    f16x8 a[4], b[4];
#pragma unroll
    for (int i = 0; i < 4; ++i)
      a[i] = *(const f16x8*)&As[(((wm + i * 16 + fr) * 32) + fq * 8) ^ xrd];
#pragma unroll
    for (int j = 0; j < 4; ++j)
      b[j] = *(const f16x8*)&Ws[(((wn + j * 16 + fr) * 32) + fq * 8) ^ xrd];
#pragma unroll
    for (int i = 0; i < 4; ++i)
#pragma unroll
      for (int j = 0; j < 4; ++j)
        acc[i][j] = __builtin_amdgcn_mfma_f32_16x16x32_f16(a[i], b[j], acc[i][j], 0, 0, 0);
    __syncthreads();
  }

#pragma unroll
  for (int j = 0; j < 4; ++j) {
    const int col = n0 + wn + j * 16 + fr;
    const float bv = bias[col];
#pragma unroll
    for (int i = 0; i < 4; ++i) {
#pragma unroll
      for (int r = 0; r < 4; ++r) {
        const int row = m0 + wm + i * 16 + fq * 4 + r;
        const f16 v = (f16)(acc[i][j][r] + bv);
        if (frag) {
          const size_t idx = (((size_t)(row >> 6) * 24 + (col >> 5)) * 4 +
                              ((row >> 4) & 3)) * 512 +
                             ((row & 15) + (((col >> 3) & 3) << 4)) * 8 + (col & 7);
          C[idx] = v;
        } else {
          C[(size_t)row * DD + col] = v;
        }
      }
    }
  }
}

// ---------------- attn11: attn8 + unroll-2 named ping-pong ----------------
// Structure of the proven 255us attn8 (dc-32 phases, one-phase-ahead Q
// prefetch, K dbuf 16KB LDS), with the av=avn copy removed by unrolling h
// by 2: even h consumes avA / prefetches avB, odd h the reverse. (256,3):
// ~90 arch VGPR + 64 AGPR = 154 <= 170 cap, no spill (tripwire: WRITE_SIZE).
// Grid 768: bid = qs*24 + kh*8 + bb; kh thirds kt {11,11,10}; H = cnt*24 even.
// Qf layout (dc-major runs): frag i of group grp at dc -> grp*49152 +
// (dc*4 + i)*512; per-wave dc-run of 4 frags is contiguous 2KB (imm offsets).
__global__ __launch_bounds__(256, 3)
void attn11(const f16* __restrict__ Qf, const f16* __restrict__ K,
            const int* __restrict__ mask, float* __restrict__ pzv,
            float* __restrict__ sdg) {
  __shared__ f16 Ks[2][128 * 32];

  const int bid = blockIdx.x;
  const int qs = bid / 24;
  const int kh = (bid % 24) >> 3;
  const int bb = bid & 7;
  const int t = threadIdx.x, l = t & 63, w = t >> 6;
  const int wq = w >> 1, wk = w & 1;
  const int fr = l & 15, fq = l >> 4;
  const int q0 = qs * 128;
  const float scale = 0.036084391824351613f;  // 1/sqrt(768)
  const int lo = kh * 11;
  const int cnt = (kh < 2) ? 11 : 10;
  const int H = cnt * 24;

  const f16* Kg = K + (size_t)bb * TT * DD;

  // Qf base: 64-row group grp = bb*64 + qs*2 + wq; lane offset l*8.
  const int grp = bb * 64 + qs * 2 + wq;
  const f16* qf = Qf + (size_t)grp * 24 * 4 * 512 + (size_t)l * 8;

  // K staging: linear 16B slots t / t+256; source col-slot pre-swizzled.
  const int c8 = ((t & 3) ^ ((t >> 3) & 3)) * 8;
  const f16* klo = Kg + (size_t)(t >> 2) * DD + c8;
  const f16* khi = klo + (size_t)64 * DD;

  // K fragment read: row*32 + (fq ^ ((fr>>1)&3))*8  (conflict-free, measured)
  const int sx = (fq ^ ((fr >> 1) & 3)) * 8;
  const int bbase = (wk * 64 + fr) * 32 + sx;

  f32x4 acc[4][4] = {};
  f32x4 zacc[4] = {};
  int im0 = 1, im1 = 1, im2 = 1, im3 = 1;
  f16x8 avA[4], avB[4];

#define STAGE(bf, h_) do { \
    const size_t o0 = (size_t)(lo + (h_) / 24) * 128 * DD + (size_t)(((h_) % 24) * 32); \
    gload16(klo + o0, &Ks[bf][w * 512]); \
    gload16(khi + o0, &Ks[bf][2048 + w * 512]); \
  } while (0)

#define QLOAD(dst, dc_) do { \
    const f16* qp_ = qf + (size_t)(dc_) * 2048; \
    _Pragma("unroll") \
    for (int i = 0; i < 4; ++i) (dst)[i] = *(const f16x8*)(qp_ + i * 512); \
  } while (0)

#define MFMA_ALL(av_, bufv) do { \
    f16x8 bv[4]; \
    _Pragma("unroll") \
    for (int j = 0; j < 4; ++j) bv[j] = *(const f16x8*)&Ks[bufv][bbase + j * 512]; \
    _Pragma("unroll") \
    for (int i = 0; i < 4; ++i) \
      _Pragma("unroll") \
      for (int j = 0; j < 4; ++j) \
        acc[i][j] = __builtin_amdgcn_mfma_f32_16x16x32_f16((av_)[i], bv[j], acc[i][j], 0, 0, 0); \
  } while (0)

  // epilogue body (dc==23 for kt): per-lane exp-sum, diag capture, acc clear
#define KT_EPILOGUE(kt_) do { \
    const float mb0 = im0 ? 0.f : -1e30f; \
    const float mb1 = im1 ? 0.f : -1e30f; \
    const float mb2 = im2 ? 0.f : -1e30f; \
    const float mb3 = im3 ? 0.f : -1e30f; \
    const bool isdiag = ((kt_) == qs); \
    _Pragma("unroll") \
    for (int i = 0; i < 4; ++i) { \
      _Pragma("unroll") \
      for (int rg = 0; rg < 4; ++rg) { \
        float v0 = fmaf(acc[i][0][rg], scale, mb0); \
        float v1 = fmaf(acc[i][1][rg], scale, mb1); \
        float v2 = fmaf(acc[i][2][rg], scale, mb2); \
        float v3 = fmaf(acc[i][3][rg], scale, mb3); \
        if (isdiag) { \
          const int rl = wq * 64 + i * 16 + fq * 4 + rg; \
          const int cl = wk * 64 + fr; \
          if (cl      == rl) sdg[(size_t)bb * TT + q0 + rl] = v0; \
          if (cl + 16 == rl) sdg[(size_t)bb * TT + q0 + rl] = v1; \
          if (cl + 32 == rl) sdg[(size_t)bb * TT + q0 + rl] = v2; \
          if (cl + 48 == rl) sdg[(size_t)bb * TT + q0 + rl] = v3; \
        } \
        zacc[i][rg] += __expf(v0) + __expf(v1) + __expf(v2) + __expf(v3); \
      } \
    } \
    _Pragma("unroll") \
    for (int i = 0; i < 4; ++i) \
      _Pragma("unroll") \
      for (int j = 0; j < 4; ++j) acc[i][j] = (f32x4)(0.f); \
  } while (0)

  // prologue: stage K(h=0); prefetch avA for h=0
  STAGE(0, 0);
  QLOAD(avA, 0);
  __syncthreads();

  for (int h2 = 0; h2 < H; h2 += 2) {
    const int kt = lo + h2 / 24, dc = h2 % 24;   // dc even: 0,2,..,22
    if (dc == 0) {  // preload mask for this kt (consumed at dc==23, odd sub)
      const int kb = bb * TT + kt * 128 + wk * 64 + fr;
      im0 = mask[kb]; im1 = mask[kb + 16]; im2 = mask[kb + 32]; im3 = mask[kb + 48];
    }

    // ---- even h (buf 0): prefetch avB(dc+1) + stage K(h2+1); MFMA(avA)
    QLOAD(avB, dc + 1);
    STAGE(1, h2 + 1);
    MFMA_ALL(avA, 0);
    __syncthreads();

    // ---- odd h (buf 1): prefetch avA(next dc) + stage K(h2+2); MFMA(avB)
    if (h2 + 2 < H) {
      QLOAD(avA, (h2 + 2) % 24);
      STAGE(0, h2 + 2);
    }
    MFMA_ALL(avB, 1);

    if (dc == 22) KT_EPILOGUE(kt);   // h2+1 has dc==23

    __syncthreads();
  }
#undef STAGE
#undef QLOAD
#undef MFMA_ALL
#undef KT_EPILOGUE

  // reduce zacc across the 16 fr-lanes; write per-(kh,wk) partial Z (6 slots)
  const int slot = kh * 2 + wk;
#pragma unroll
  for (int i = 0; i < 4; ++i) {
#pragma unroll
    for (int rg = 0; rg < 4; ++rg) {
      float z = zacc[i][rg];
#pragma unroll
      for (int off = 1; off < 16; off <<= 1) z += __shfl_xor(z, off);
      if (fr == 0) {
        const int row = wq * 64 + i * 16 + fq * 4 + rg;
        pzv[(size_t)slot * MM + bb * TT + q0 + row] = z;
      }
    }
  }
}

// ---------------- merge 6 partials -> wdiag ----------------
__global__ void merge6(const float* __restrict__ pz, const float* __restrict__ sdg,
                       float* __restrict__ wdiag) {
  int i = blockIdx.x * 256 + threadIdx.x;
  if (i >= MM) return;
  float Z = 0.f;
#pragma unroll
  for (int s = 0; s < 6; ++s) Z += pz[(size_t)s * MM + i];
  wdiag[i] = __expf(sdg[i]) / Z;
}

// ---------------- output ----------------
__global__ void zero_out(float* out, int n) {
  int i = blockIdx.x * 256 + threadIdx.x;
  if (i < n) out[i] = 0.f;
}

// out[b,d] = sum_t X[b,t,d] * wdiag[b,t]
__global__ __launch_bounds__(256)
void out_gemv(const float* __restrict__ X, const float* __restrict__ wdiag,
              float* __restrict__ out) {
  __shared__ float wsm[256];
  const int b = blockIdx.z;
  const int d = blockIdx.y * 256 + threadIdx.x;
  const int tbase = blockIdx.x * 256;
  wsm[threadIdx.x] = wdiag[b * TT + tbase + threadIdx.x];
  __syncthreads();
  float acc = 0.f;
  const float* xp = X + (size_t)(b * TT + tbase) * DD + d;
#pragma unroll 4
  for (int i = 0; i < 256; ++i) acc += xp[(size_t)i * DD] * wsm[i];
  atomicAdd(&out[b * DD + d], acc);
}

extern "C" void kernel_launch(void* const* d_in, const int* in_sizes, int n_in,
                              void* d_out, int out_size, void* d_ws, size_t ws_size,
                              hipStream_t stream) {
  const float* X    = (const float*)d_in[0];
  const int*   mask = (const int*)d_in[1];
  const float* Wq_w = (const float*)d_in[2];
  const float* Wq_b = (const float*)d_in[3];
  const float* Wk_w = (const float*)d_in[4];
  const float* Wk_b = (const float*)d_in[5];
  float* out = (float*)d_out;

  // workspace layout (~103 MB):
  // [Qf 50.3MB][Kh 50.3MB][Wqh|Wkh 2.36MB -- aliased after proj by pz|sdg|wdiag]
  f16* Qf  = (f16*)d_ws;                      // fragment-major Q
  f16* Kh  = Qf + (size_t)MM * DD;            // row-major K
  f16* Wqh = Kh + (size_t)MM * DD;            // f16 weights (dead after proj)
  f16* Wkh = Wqh + (size_t)DD * DD;
  float* pz    = (float*)Wqh;                 // alias: written by attn11 after proj reads
  float* sdg   = pz + 6 * (size_t)MM;
  float* wdiag = sdg + MM;

  cvt_f32_f16<<<288, 256, 0, stream>>>(Wq_w, Wqh, DD * DD);
  cvt_f32_f16<<<288, 256, 0, stream>>>(Wk_w, Wkh, DD * DD);

  proj_gemm<<<dim3(256, 6), 256, 0, stream>>>(X, Wqh, Wq_b, Qf, 1);
  proj_gemm<<<dim3(256, 6), 256, 0, stream>>>(X, Wkh, Wk_b, Kh, 0);

  attn11<<<768, 256, 0, stream>>>(Qf, Kh, mask, pz, sdg);

  merge6<<<128, 256, 0, stream>>>(pz, sdg, wdiag);

  zero_out<<<24, 256, 0, stream>>>(out, BB * DD);
  out_gemv<<<dim3(16, 3, 8), 256, 0, stream>>>(X, wdiag, out);
}